// Round 2
// baseline (501.494 us; speedup 1.0000x reference)
//
#include <hip/hip_runtime.h>
#include <hip/hip_cooperative_groups.h>
#include <math.h>

namespace cg = cooperative_groups;

// problem dims: B=8, L=96, D=512, R=64, NTYPES=47, NLAYERS=3
// ws float offsets
#define SEQ_OFF  0
#define AGG_OFF  393216
#define G_OFF    786432
#define POOL_OFF 788736
#define ENSW_OFF 801024
#define CNT_OFF  801028

#define SCALE 0.044194173824159216f   // 1/sqrt(512)
#define INVS  0.9995003746879289f     // 1/sqrt(1.001)

#define F4FMA(acc, s, ww) { acc.x = fmaf(s, ww.x, acc.x); acc.y = fmaf(s, ww.y, acc.y); \
                            acc.z = fmaf(s, ww.z, acc.z); acc.w = fmaf(s, ww.w, acc.w); }

__device__ __forceinline__ float wave_sum(float v) {
  #pragma unroll
  for (int o = 32; o; o >>= 1) v += __shfl_xor(v, o);
  return v;
}
__device__ __forceinline__ float wave_max(float v) {
  #pragma unroll
  for (int o = 32; o; o >>= 1) v = fmaxf(v, __shfl_xor(v, o));
  return v;
}

// pools[b,d] = (sum_i mask*seq) / cnt(b).  u in [0,16): b = u>>1, d-half = u&1
__device__ __forceinline__ void pool_unit(int u, int tid, const float* __restrict__ seq,
                                          const float* __restrict__ mask,
                                          const float* __restrict__ rcnt,
                                          float* __restrict__ dst) {
  const int b = u >> 1;
  const int d = (u & 1) * 256 + tid;
  float acc = 0.f;
  #pragma unroll 4
  for (int i = 0; i < 96; ++i)
    acc = fmaf(mask[b*96 + i], seq[(b*96 + i)*512 + d], acc);
  dst[b*512 + d] = acc * rcnt[b];
}

__global__ __launch_bounds__(256) void k_fused(
    const float* __restrict__ text, const float* __restrict__ mask,
    const float* __restrict__ adj, const float* __restrict__ E,
    const float* __restrict__ gamma, const float* __restrict__ beta,
    const float* __restrict__ Wst, const float* __restrict__ bst,
    const float* __restrict__ ensl, const float* __restrict__ fcW,
    const float* __restrict__ fcb, const int* __restrict__ dv,
    float* __restrict__ ws, float* __restrict__ out)
{
  cg::grid_group grid = cg::this_grid();
  __shared__ __align__(16) float smem[7680];   // 30720 B: gemm s_a (6144 f) + s_red (1536 f)
  const int blk = blockIdx.x, tid = threadIdx.x;
  const int w = tid >> 6, lane = tid & 63;

  float* seq  = ws + SEQ_OFF;
  float* agg  = ws + AGG_OFF;
  float* G    = ws + G_OFF;
  float* pool = ws + POOL_OFF;
  float* ensw = ws + ENSW_OFF;
  float* rcnt = ws + CNT_OFF;

  // ---------------- P0: seq-norm + G table + counts + ensemble softmax ----------------
  {
    const float4* T4 = (const float4*)text;
    float4* S4 = (float4*)seq;
    const float4* G4 = (const float4*)gamma;
    const float4* B4 = (const float4*)beta;
    for (int i4 = blk*256 + tid; i4 < 98304; i4 += 65536) {
      float4 t = T4[i4];
      const int gi = i4 & 127;
      float4 g4 = G4[gi], b4 = B4[gi];
      float4 o;
      o.x = fmaf(t.x, g4.x * INVS, b4.x);
      o.y = fmaf(t.y, g4.y * INVS, b4.y);
      o.z = fmaf(t.z, g4.z * INVS, b4.z);
      o.w = fmaf(t.w, g4.w * INVS, b4.w);
      S4[i4] = o;
    }
    // G[t1,t2] = dot(E[t1], E[t2])  (one wave per entry)
    for (int g = blk*4 + w; g < 2209; g += 1024) {
      const int t1 = g / 47, t2 = g - t1*47;
      const float4* e1 = (const float4*)E + t1*128;
      const float4* e2 = (const float4*)E + t2*128;
      float4 a0 = e1[lane*2], a1 = e1[lane*2 + 1];
      float4 b0 = e2[lane*2], b1 = e2[lane*2 + 1];
      float d = a0.x*b0.x;
      d = fmaf(a0.y, b0.y, d); d = fmaf(a0.z, b0.z, d); d = fmaf(a0.w, b0.w, d);
      d = fmaf(a1.x, b1.x, d); d = fmaf(a1.y, b1.y, d);
      d = fmaf(a1.z, b1.z, d); d = fmaf(a1.w, b1.w, d);
      d = wave_sum(d);
      if (lane == 0) G[g] = d;
    }
    if (blk == 0) {
      if (tid < 8) {
        float c = 0.f;
        for (int i = 0; i < 96; ++i) c += (mask[tid*96 + i] != 0.f) ? 1.f : 0.f;
        rcnt[tid] = 1.f / (c + 1e-10f);
      }
      if (tid == 8) {
        const float e0 = ensl[0], e1 = ensl[1], e2 = ensl[2];
        const float m = fmaxf(e0, fmaxf(e1, e2));
        const float x0 = expf(e0 - m), x1 = expf(e1 - m), x2 = expf(e2 - m);
        const float s = x0 + x1 + x2;
        ensw[0] = x0/s; ensw[1] = x1/s; ensw[2] = x2/s;
      }
    }
  }
  grid.sync();

  for (int l = 0; l < 3; ++l) {
    // ---------------- attn (blocks 0..191), pool(l-1) on blocks 192..207 ----------------
    if (blk < 192) {
      const int bb = blk / 24;
      const int i = (blk - bb*24)*4 + w;        // this wave's query row
      const float4* seq4 = (const float4*)seq;
      const float4* q4 = seq4 + (bb*96 + i)*128;
      const float4 q0 = q4[lane*2], q1 = q4[lane*2 + 1];
      float sc0 = -3.0e38f, sc1 = -3.0e38f;     // lane holds score[j=lane], score[j=64+lane]
      #pragma unroll 4
      for (int j = 0; j < 96; ++j) {
        const float4* k4 = seq4 + (bb*96 + j)*128;
        float4 x0 = k4[lane*2], x1 = k4[lane*2 + 1];
        float d = q0.x*x0.x;
        d = fmaf(q0.y, x0.y, d); d = fmaf(q0.z, x0.z, d); d = fmaf(q0.w, x0.w, d);
        d = fmaf(q1.x, x1.x, d); d = fmaf(q1.y, x1.y, d);
        d = fmaf(q1.z, x1.z, d); d = fmaf(q1.w, x1.w, d);
        d = wave_sum(d);
        sc0 = (lane == j)      ? d : sc0;
        sc1 = (lane == j - 64) ? d : sc1;
      }
      const int* dvb = dv + bb*9216;
      {
        const int v1 = dvb[i*96 + lane];        // dv[b,i,j]  (coalesced)
        const int v2 = dvb[lane*96 + i];        // dv[b,j,i]  (scattered, L2)
        const float bs = (v1 > 0 && v2 > 0) ? G[v1*47 + v2] : 0.f;
        sc0 = (sc0 + bs) * SCALE;
      }
      if (lane < 32) {
        const int v1 = dvb[i*96 + 64 + lane];
        const int v2 = dvb[(64 + lane)*96 + i];
        const float bs = (v1 > 0 && v2 > 0) ? G[v1*47 + v2] : 0.f;
        sc1 = (sc1 + bs) * SCALE;
      }
      const float mx = wave_max(fmaxf(sc0, sc1));
      const float e0 = expf(sc0 - mx);
      const float e1 = (lane < 32) ? expf(sc1 - mx) : 0.f;
      const float s = wave_sum(e0 + e1);
      const float inv = 1.f / s;
      const float* ad = adj + (bb*96 + i)*96;
      const float a0 = e0 * inv * ad[lane];
      const float a1 = (lane < 32) ? e1 * inv * ad[64 + lane] : 0.f;
      // agg[i,d] = sum_j a_j * (seq[j,d] + (dv[b,j,i]>0 ? E[dv[b,j,i],d] : 0))
      float4 ac0 = {0,0,0,0}, ac1 = {0,0,0,0};
      for (int j = 0; j < 96; ++j) {
        const float a = (j < 64) ? __shfl(a0, j) : __shfl(a1, j - 64);
        if (a != 0.f) {                          // wave-uniform, ~10% taken
          const float4* k4 = seq4 + (bb*96 + j)*128;
          float4 x0 = k4[lane*2], x1 = k4[lane*2 + 1];
          const int vt = dvb[j*96 + i];
          if (vt > 0) {
            const float4* er = (const float4*)E + vt*128;
            const float4 y0 = er[lane*2], y1 = er[lane*2 + 1];
            x0.x += y0.x; x0.y += y0.y; x0.z += y0.z; x0.w += y0.w;
            x1.x += y1.x; x1.y += y1.y; x1.z += y1.z; x1.w += y1.w;
          }
          F4FMA(ac0, a, x0);
          F4FMA(ac1, a, x1);
        }
      }
      float4* o4 = (float4*)agg + (bb*96 + i)*128;
      o4[lane*2] = ac0;
      o4[lane*2 + 1] = ac1;
    } else if (l > 0 && blk < 208) {
      pool_unit(blk - 192, tid, seq, mask, rcnt, pool + (l-1)*4096);
    }
    grid.sync();

    // ---------------- gemm: seq = relu(agg @ W_l + b_l); 256 tiles of 12x128 ----------------
    {
      const float* Wl = Wst + l*262144;
      const int rt = blk >> 2, ct = blk & 3;
      const int r0 = rt*12, c0 = ct*128;
      const float4* A4 = (const float4*)agg;
      float4* sa4 = (float4*)smem;                 // 12 x 128 f4
      float4* sred4 = (float4*)(smem + 6144);      // 128 thr x 3 f4
      #pragma unroll
      for (int idx = tid; idx < 1536; idx += 256)
        sa4[idx] = A4[r0*128 + idx];
      __syncthreads();
      const int kh = tid >> 7, tt = tid & 127;
      const int rg = tt >> 5, cg = tt & 31;
      const int rg3 = rg*3;
      const float4* W4 = (const float4*)Wl + (c0 >> 2) + cg;   // index by k*128
      float4 ac0 = {0,0,0,0}, ac1 = {0,0,0,0}, ac2 = {0,0,0,0};
      const int kbeg = kh*256;
      #pragma unroll 2
      for (int kc = kbeg; kc < kbeg + 256; kc += 4) {
        const int kq = kc >> 2;
        const float4 a0 = sa4[(rg3+0)*128 + kq];   // LDS broadcast (2 addrs/wave)
        const float4 a1 = sa4[(rg3+1)*128 + kq];
        const float4 a2 = sa4[(rg3+2)*128 + kq];
        const float4 w0 = W4[(kc+0)*128];          // global, L1-resident
        const float4 w1 = W4[(kc+1)*128];
        const float4 w2 = W4[(kc+2)*128];
        const float4 w3 = W4[(kc+3)*128];
        F4FMA(ac0, a0.x, w0); F4FMA(ac0, a0.y, w1); F4FMA(ac0, a0.z, w2); F4FMA(ac0, a0.w, w3);
        F4FMA(ac1, a1.x, w0); F4FMA(ac1, a1.y, w1); F4FMA(ac1, a1.z, w2); F4FMA(ac1, a1.w, w3);
        F4FMA(ac2, a2.x, w0); F4FMA(ac2, a2.y, w1); F4FMA(ac2, a2.z, w2); F4FMA(ac2, a2.w, w3);
      }
      if (kh) {
        sred4[tt*3 + 0] = ac0; sred4[tt*3 + 1] = ac1; sred4[tt*3 + 2] = ac2;
      }
      __syncthreads();
      if (!kh) {
        const float4 r0v = sred4[tt*3 + 0], r1v = sred4[tt*3 + 1], r2v = sred4[tt*3 + 2];
        ac0.x += r0v.x; ac0.y += r0v.y; ac0.z += r0v.z; ac0.w += r0v.w;
        ac1.x += r1v.x; ac1.y += r1v.y; ac1.z += r1v.z; ac1.w += r1v.w;
        ac2.x += r2v.x; ac2.y += r2v.y; ac2.z += r2v.z; ac2.w += r2v.w;
        const float4 bv = ((const float4*)(bst + l*512 + c0))[cg];
        float4 o0, o1, o2;
        o0.x = fmaxf(ac0.x + bv.x, 0.f); o0.y = fmaxf(ac0.y + bv.y, 0.f);
        o0.z = fmaxf(ac0.z + bv.z, 0.f); o0.w = fmaxf(ac0.w + bv.w, 0.f);
        o1.x = fmaxf(ac1.x + bv.x, 0.f); o1.y = fmaxf(ac1.y + bv.y, 0.f);
        o1.z = fmaxf(ac1.z + bv.z, 0.f); o1.w = fmaxf(ac1.w + bv.w, 0.f);
        o2.x = fmaxf(ac2.x + bv.x, 0.f); o2.y = fmaxf(ac2.y + bv.y, 0.f);
        o2.z = fmaxf(ac2.z + bv.z, 0.f); o2.w = fmaxf(ac2.w + bv.w, 0.f);
        ((float4*)(seq + (r0+rg3+0)*512 + c0))[cg] = o0;
        ((float4*)(seq + (r0+rg3+1)*512 + c0))[cg] = o1;
        ((float4*)(seq + (r0+rg3+2)*512 + c0))[cg] = o2;
      }
    }
    grid.sync();
  }

  // ---------------- pool for layer 2 ----------------
  if (blk < 16) pool_unit(blk, tid, seq, mask, rcnt, pool + 2*4096);
  grid.sync();

  // ---------------- final: out = (sum_l w_l * pool_l) @ fcW + fcb ----------------
  if (blk < 8) {
    const int r = tid & 63, dq = tid >> 6;
    const float w0 = ensw[0], w1 = ensw[1], w2 = ensw[2];
    const float* p0 = pool + blk*512;
    const float* p1 = pool + 4096 + blk*512;
    const float* p2 = pool + 8192 + blk*512;
    float acc = 0.f;
    #pragma unroll 4
    for (int d = dq*128; d < dq*128 + 128; ++d) {
      const float e = w0*p0[d] + w1*p1[d] + w2*p2[d];
      acc = fmaf(e, fcW[d*64 + r], acc);
    }
    smem[tid] = acc;
    __syncthreads();
    if (tid < 64)
      out[blk*64 + tid] = fcb[tid] + smem[tid] + smem[64 + tid] + smem[128 + tid] + smem[192 + tid];
  }
}

extern "C" void kernel_launch(void* const* d_in, const int* in_sizes, int n_in,
                              void* d_out, int out_size, void* d_ws, size_t ws_size,
                              hipStream_t stream)
{
  const float* text  = (const float*)d_in[0];
  const float* mask  = (const float*)d_in[1];
  const float* adj   = (const float*)d_in[2];
  const float* E     = (const float*)d_in[3];
  const float* gamma = (const float*)d_in[4];
  const float* beta  = (const float*)d_in[5];
  const float* Wst   = (const float*)d_in[6];
  const float* bst   = (const float*)d_in[7];
  const float* ensl  = (const float*)d_in[8];
  const float* fcW   = (const float*)d_in[9];
  const float* fcb   = (const float*)d_in[10];
  const int*   dv    = (const int*)d_in[11];
  float* ws  = (float*)d_ws;
  float* out = (float*)d_out;

  void* kargs[] = {
    (void*)&text, (void*)&mask, (void*)&adj, (void*)&E, (void*)&gamma, (void*)&beta,
    (void*)&Wst, (void*)&bst, (void*)&ensl, (void*)&fcW, (void*)&fcb, (void*)&dv,
    (void*)&ws, (void*)&out
  };
  hipLaunchCooperativeKernel((const void*)k_fused, dim3(256), dim3(256),
                             kargs, 0, stream);
}

// Round 5
// 185.367 us; speedup vs baseline: 2.7054x; 2.7054x over previous
//
#include <hip/hip_runtime.h>
#include <math.h>

// dims: B=8, L=96, D=512, R=64, NTYPES=47, NLAYERS=3
#define SCALE 0.044194173824159216f   // 1/sqrt(512)
#define INVS  0.9995003746879289f     // 1/sqrt(1.001)

// ws float offsets
#define SEQ_OFF  0          // 393216
#define AGG_OFF  393216     // 393216
#define G_OFF    786432     // 2209 (pad 2304)
#define POOL_OFF 788736     // 3*8*512
#define ENSW_OFF 801024     // 3
#define CNT_OFF  801028     // 8

#define F4FMA(acc, s, ww) { acc.x = fmaf(s, ww.x, acc.x); acc.y = fmaf(s, ww.y, acc.y); \
                            acc.z = fmaf(s, ww.z, acc.z); acc.w = fmaf(s, ww.w, acc.w); }

__device__ __forceinline__ float wave_sum(float v) {
  #pragma unroll
  for (int o = 32; o; o >>= 1) v += __shfl_xor(v, o);
  return v;
}
__device__ __forceinline__ float wave_max(float v) {
  #pragma unroll
  for (int o = 32; o; o >>= 1) v = fmaxf(v, __shfl_xor(v, o));
  return v;
}

// ---------------------------------------------------------------------------
// prep: seq-norm + G table + rcnt + ensemble softmax.  grid 512x256
// ---------------------------------------------------------------------------
__global__ __launch_bounds__(256) void k_prep(
    const float* __restrict__ text, const float* __restrict__ mask,
    const float* __restrict__ E, const float* __restrict__ gamma,
    const float* __restrict__ beta, const float* __restrict__ ensl,
    float* __restrict__ ws)
{
  const int blk = blockIdx.x, tid = threadIdx.x;
  const int gt = blk * 256 + tid;
  {
    const float4* T4 = (const float4*)text;
    float4* S4 = (float4*)(ws + SEQ_OFF);
    const float4* G4 = (const float4*)gamma;
    const float4* B4 = (const float4*)beta;
    for (int i4 = gt; i4 < 98304; i4 += 512 * 256) {
      float4 t = T4[i4];
      const int gi = i4 & 127;
      const float4 g4 = G4[gi], b4 = B4[gi];
      float4 o;
      o.x = fmaf(t.x, g4.x * INVS, b4.x);
      o.y = fmaf(t.y, g4.y * INVS, b4.y);
      o.z = fmaf(t.z, g4.z * INVS, b4.z);
      o.w = fmaf(t.w, g4.w * INVS, b4.w);
      S4[i4] = o;
    }
  }
  // G[t1,t2] = dot(E[t1],E[t2]); one wave per entry
  const int wg = gt >> 6, lane = tid & 63;
  float* G = ws + G_OFF;
  for (int g = wg; g < 2209; g += 2048) {
    const int t1 = g / 47, t2 = g - t1 * 47;
    const float4* e1 = (const float4*)E + t1 * 128;
    const float4* e2 = (const float4*)E + t2 * 128;
    const float4 a0 = e1[lane * 2], a1 = e1[lane * 2 + 1];
    const float4 b0 = e2[lane * 2], b1 = e2[lane * 2 + 1];
    float d = a0.x * b0.x;
    d = fmaf(a0.y, b0.y, d); d = fmaf(a0.z, b0.z, d); d = fmaf(a0.w, b0.w, d);
    d = fmaf(a1.x, b1.x, d); d = fmaf(a1.y, b1.y, d);
    d = fmaf(a1.z, b1.z, d); d = fmaf(a1.w, b1.w, d);
    d = wave_sum(d);
    if (lane == 0) G[g] = d;
  }
  if (blk == 0) {
    if (tid < 8) {
      float c = 0.f;
      for (int i = 0; i < 96; ++i) c += (mask[tid * 96 + i] != 0.f) ? 1.f : 0.f;
      (ws + CNT_OFF)[tid] = 1.f / (c + 1e-10f);
    }
    if (tid == 8) {
      const float e0 = ensl[0], e1 = ensl[1], e2 = ensl[2];
      const float m = fmaxf(e0, fmaxf(e1, e2));
      const float x0 = expf(e0 - m), x1 = expf(e1 - m), x2 = expf(e2 - m);
      const float s = x0 + x1 + x2;
      (ws + ENSW_OFF)[0] = x0 / s;
      (ws + ENSW_OFF)[1] = x1 / s;
      (ws + ENSW_OFF)[2] = x2 / s;
    }
  }
}

// pools[b,d] = (sum_i mask*seq)/cnt(b); u in [0,16): b=u>>1, d-half=u&1
__device__ __forceinline__ void pool_unit(int u, int tid,
    const float* __restrict__ seq, const float* __restrict__ mask,
    const float* __restrict__ rcnt, float* __restrict__ dst)
{
  const int b = u >> 1;
  const int d = (u & 1) * 256 + tid;
  float acc = 0.f;
  #pragma unroll 4
  for (int i = 0; i < 96; ++i)
    acc = fmaf(mask[b * 96 + i], seq[(b * 96 + i) * 512 + d], acc);
  dst[b * 512 + d] = acc * rcnt[b];
}

// ---------------------------------------------------------------------------
// attn: block per query row (blk = i*8 + b -> XCD b holds batch b).
// 4 waves: j-split scores -> LDS -> softmax(wave0) -> d-split agg.
// blocks 768..783: pool of previous layer's seq (when do_pool).
// grid 784x256
// ---------------------------------------------------------------------------
__global__ __launch_bounds__(256) void k_attn(
    const float* __restrict__ seq, float* __restrict__ agg,
    const float* __restrict__ adj, const float* __restrict__ E,
    const int* __restrict__ dv, const float* __restrict__ ws,
    const float* __restrict__ mask, float* __restrict__ pool_dst, int do_pool)
{
  const int blk = blockIdx.x, tid = threadIdx.x;
  if (blk >= 768) {
    if (do_pool) pool_unit(blk - 768, tid, seq, mask, ws + CNT_OFF, pool_dst);
    return;
  }
  __shared__ float s_sc[96];
  __shared__ float s_at[96];
  __shared__ int   s_vt[96];
  const int b = blk & 7, i = blk >> 3;
  const int w = tid >> 6, lane = tid & 63;
  const float* G = ws + G_OFF;
  const float4* seq4 = (const float4*)seq + (size_t)b * 96 * 128;

  const float4 q0 = seq4[i * 128 + lane * 2];
  const float4 q1 = seq4[i * 128 + lane * 2 + 1];
  // scores: wave w handles j = w, w+4, ...
  #pragma unroll 2
  for (int j = w; j < 96; j += 4) {
    const float4 x0 = seq4[j * 128 + lane * 2];
    const float4 x1 = seq4[j * 128 + lane * 2 + 1];
    float d = q0.x * x0.x;
    d = fmaf(q0.y, x0.y, d); d = fmaf(q0.z, x0.z, d); d = fmaf(q0.w, x0.w, d);
    d = fmaf(q1.x, x1.x, d); d = fmaf(q1.y, x1.y, d);
    d = fmaf(q1.z, x1.z, d); d = fmaf(q1.w, x1.w, d);
    d = wave_sum(d);
    if (lane == 0) s_sc[j] = d;
  }
  __syncthreads();
  // dep bias + scale; stash transposed dv for agg
  const int* dvb = dv + b * 9216;
  if (tid < 96) {
    const int v1 = dvb[i * 96 + tid];
    const int v2 = dvb[tid * 96 + i];
    s_vt[tid] = v2;
    const float bs = (v1 > 0 && v2 > 0) ? G[v1 * 47 + v2] : 0.f;
    s_sc[tid] = (s_sc[tid] + bs) * SCALE;
  }
  __syncthreads();
  if (w == 0) {
    const float v0 = s_sc[lane];
    const float v1 = (lane < 32) ? s_sc[64 + lane] : -3.0e38f;
    const float mx = wave_max(fmaxf(v0, v1));
    const float e0 = expf(v0 - mx);
    const float e1 = (lane < 32) ? expf(v1 - mx) : 0.f;
    const float s = wave_sum(e0 + e1);
    const float inv = 1.f / s;
    const float* ad = adj + (b * 96 + i) * 96;
    s_at[lane] = e0 * inv * ad[lane];
    if (lane < 32) s_at[64 + lane] = e1 * inv * ad[64 + lane];
  }
  __syncthreads();
  // agg: wave w owns d in [128w,128w+128); lane -> float2
  const int d2 = w * 64 + lane;                       // float2 index
  const float2* seq2 = (const float2*)seq + (size_t)b * 96 * 256;
  const float2* E2 = (const float2*)E;
  float ax = 0.f, ay = 0.f;
  for (int j = 0; j < 96; ++j) {
    const float a = s_at[j];
    if (a != 0.f) {                                   // block-uniform, ~10% taken
      float2 x = seq2[j * 256 + d2];
      const int vt = s_vt[j];
      if (vt > 0) {
        const float2 e2v = E2[vt * 256 + d2];
        x.x += e2v.x; x.y += e2v.y;
      }
      ax = fmaf(a, x.x, ax);
      ay = fmaf(a, x.y, ay);
    }
  }
  float2 o; o.x = ax; o.y = ay;
  ((float2*)agg)[(size_t)(b * 96 + i) * 256 + d2] = o;
}

// ---------------------------------------------------------------------------
// gemm: Out = relu(A @ W + bias). Tiles 6x128, 512 blocks (2/CU).
// blk = b + 8*rr + 128*ct  (batch-XCD pinned). threads = 32 colf4 x 8 kq.
// ---------------------------------------------------------------------------
__global__ __launch_bounds__(256) void k_gemm(
    const float* __restrict__ A, const float* __restrict__ W,
    const float* __restrict__ bias, float* __restrict__ Out)
{
  __shared__ __align__(16) float s_a[6 * 512];        // 12 KB
  __shared__ __align__(16) float4 s_p[8 * 6 * 32];    // 24 KB
  const int blk = blockIdx.x, tid = threadIdx.x;
  const int b = blk & 7, rr = (blk >> 3) & 15, ct = blk >> 7;
  const int rt = b * 16 + rr;
  const int r0 = rt * 6, c0 = ct * 128;
  {
    const float4* A4 = (const float4*)(A + r0 * 512);
    float4* sa4 = (float4*)s_a;
    sa4[tid] = A4[tid];
    sa4[tid + 256] = A4[tid + 256];
    sa4[tid + 512] = A4[tid + 512];
  }
  __syncthreads();
  const int cq = tid & 31, kq = tid >> 5;
  const float4* W4 = (const float4*)W + ct * 32 + cq;   // + k*128
  float4 acc[6];
  #pragma unroll
  for (int r = 0; r < 6; ++r) { acc[r].x = 0.f; acc[r].y = 0.f; acc[r].z = 0.f; acc[r].w = 0.f; }
  const float4* sa4 = (const float4*)s_a;
  #pragma unroll 2
  for (int k4 = kq * 16; k4 < kq * 16 + 16; ++k4) {
    const float4 w0 = W4[(k4 * 4 + 0) * 128];
    const float4 w1 = W4[(k4 * 4 + 1) * 128];
    const float4 w2 = W4[(k4 * 4 + 2) * 128];
    const float4 w3 = W4[(k4 * 4 + 3) * 128];
    #pragma unroll
    for (int r = 0; r < 6; ++r) {
      const float4 a4 = sa4[r * 128 + k4];
      F4FMA(acc[r], a4.x, w0); F4FMA(acc[r], a4.y, w1);
      F4FMA(acc[r], a4.z, w2); F4FMA(acc[r], a4.w, w3);
    }
  }
  #pragma unroll
  for (int r = 0; r < 6; ++r) s_p[(kq * 6 + r) * 32 + cq] = acc[r];
  __syncthreads();
  if (tid < 192) {
    const int r = tid >> 5, c = tid & 31;
    float4 s = s_p[r * 32 + c];
    #pragma unroll
    for (int q = 1; q < 8; ++q) {
      const float4 p = s_p[(q * 6 + r) * 32 + c];
      s.x += p.x; s.y += p.y; s.z += p.z; s.w += p.w;
    }
    const float4 bv = ((const float4*)(bias + c0))[c];
    float4 o;
    o.x = fmaxf(s.x + bv.x, 0.f);
    o.y = fmaxf(s.y + bv.y, 0.f);
    o.z = fmaxf(s.z + bv.z, 0.f);
    o.w = fmaxf(s.w + bv.w, 0.f);
    ((float4*)(Out + (size_t)(r0 + r) * 512 + c0))[c] = o;
  }
}

// ---------------------------------------------------------------------------
// final: pool2 (per block) + ensemble + fc.  grid 8x256
// ---------------------------------------------------------------------------
__global__ __launch_bounds__(256) void k_final(
    const float* __restrict__ seq, const float* __restrict__ mask,
    const float* __restrict__ ws, const float* __restrict__ fcW,
    const float* __restrict__ fcb, float* __restrict__ out)
{
  __shared__ float s_ens[512];
  __shared__ float s_red[256];
  const int b = blockIdx.x, tid = threadIdx.x;
  const float* ensw = ws + ENSW_OFF;
  const float* rcnt = ws + CNT_OFF;
  const float* p0 = ws + POOL_OFF + b * 512;
  const float* p1 = ws + POOL_OFF + 4096 + b * 512;
  float2 acc; acc.x = 0.f; acc.y = 0.f;
  const float2* seqb2 = (const float2*)(seq + (size_t)b * 96 * 512);
  #pragma unroll 4
  for (int i = 0; i < 96; ++i) {
    const float m = mask[b * 96 + i];
    const float2 x = seqb2[i * 256 + tid];
    acc.x = fmaf(m, x.x, acc.x);
    acc.y = fmaf(m, x.y, acc.y);
  }
  const float rc = rcnt[b];
  const float w0 = ensw[0], w1 = ensw[1], w2 = ensw[2];
  s_ens[tid * 2]     = w0 * p0[tid * 2]     + w1 * p1[tid * 2]     + w2 * acc.x * rc;
  s_ens[tid * 2 + 1] = w0 * p0[tid * 2 + 1] + w1 * p1[tid * 2 + 1] + w2 * acc.y * rc;
  __syncthreads();
  const int r = tid & 63, dq = tid >> 6;
  float a = 0.f;
  #pragma unroll 4
  for (int d = dq * 128; d < dq * 128 + 128; ++d)
    a = fmaf(s_ens[d], fcW[d * 64 + r], a);
  s_red[tid] = a;
  __syncthreads();
  if (tid < 64)
    out[b * 64 + tid] = fcb[tid] + s_red[tid] + s_red[64 + tid]
                      + s_red[128 + tid] + s_red[192 + tid];
}

extern "C" void kernel_launch(void* const* d_in, const int* in_sizes, int n_in,
                              void* d_out, int out_size, void* d_ws, size_t ws_size,
                              hipStream_t stream)
{
  const float* text  = (const float*)d_in[0];
  const float* mask  = (const float*)d_in[1];
  const float* adj   = (const float*)d_in[2];
  const float* E     = (const float*)d_in[3];
  const float* gamma = (const float*)d_in[4];
  const float* beta  = (const float*)d_in[5];
  const float* Wst   = (const float*)d_in[6];
  const float* bst   = (const float*)d_in[7];
  const float* ensl  = (const float*)d_in[8];
  const float* fcW   = (const float*)d_in[9];
  const float* fcb   = (const float*)d_in[10];
  const int*   dv    = (const int*)d_in[11];
  float* ws  = (float*)d_ws;
  float* out = (float*)d_out;

  float* seq = ws + SEQ_OFF;
  float* agg = ws + AGG_OFF;

  k_prep<<<dim3(512), dim3(256), 0, stream>>>(text, mask, E, gamma, beta, ensl, ws);
  for (int l = 0; l < 3; ++l) {
    k_attn<<<dim3(784), dim3(256), 0, stream>>>(
        seq, agg, adj, E, dv, ws, mask,
        ws + POOL_OFF + (l > 0 ? (l - 1) * 4096 : 0), l > 0 ? 1 : 0);
    k_gemm<<<dim3(512), dim3(256), 0, stream>>>(
        agg, Wst + l * 262144, bst + l * 512, seq);
  }
  k_final<<<dim3(8), dim3(256), 0, stream>>>(seq, mask, ws, fcW, fcb, out);
}